// Round 4
// baseline (1683.373 us; speedup 1.0000x reference)
//
#include <hip/hip_runtime.h>
#include <cstddef>

// TransitionDown: B=16 clouds, P=4096 pts, S=1024 fps samples, K=16 knn,
// IN_F=256, OUT_F=512.
//
// SINGLE mega-kernel, flag-sequenced. v2: union un-padded (69.7 KB -> 2
// blocks/CU, launch_bounds(512,4) pins VGPR<=128) and KNN sliced into
// 128-query chunks matching the FPS publish granularity; the only
// FPS-end-dependent work (chunk 7) is dispatched last and fine-grained.
// Block-index layout (producers strictly before consumers):
//   [0,16)        FPS (round-0 core) + publish every 128 samples
//   [16,1040)     MLP GEMM fp32 -> h bf16
//   [1040,1296)   BN partial sums (spin: gemm)
//   [1296]        BN finalize (spin: stats)
//   [1297,2193)   KNN chunks 0..6 (7x16x8 blocks of 128q x 512c)
//   [2193,2641)   merge groups 0..27 (32q, 8-seg exact merge)
//   [2641,4433)   maxpool queries [0,896) (8q/block)
//   [4433,4561)   KNN chunk 7 (16x8)
//   [4561,4625)   merge groups 28..31
//   [4625,4881)   maxpool queries [896,1024)
// flags: [0..15] fps progress (chunks done), [16] gemm cnt, [17] stats cnt,
// [18] bnfin, [32+b*8+c] knn seg cnt (target 8), [192+b*32+g] merge done.

#define TD_B   16
#define TD_P   4096
#define TD_S   1024
#define TD_K   16
#define TD_INF 256
#define TD_OUTF 512

typedef __attribute__((ext_vector_type(8))) _Float16 half8;
typedef __attribute__((ext_vector_type(4))) float    f32x4;
typedef __attribute__((ext_vector_type(2))) float    v2f;

__device__ __forceinline__ unsigned short f2bf(float x) {
    unsigned u = __float_as_uint(x);
    unsigned r = (u + 0x7fffu + ((u >> 16) & 1u)) >> 16;   // RNE
    return (unsigned short)r;
}

__device__ __forceinline__ int ld_acq(const int* p) {
    return __hip_atomic_load(p, __ATOMIC_ACQUIRE, __HIP_MEMORY_SCOPE_AGENT);
}
__device__ __forceinline__ void st_rel(int* p, int v) {
    __hip_atomic_store(p, v, __ATOMIC_RELEASE, __HIP_MEMORY_SCOPE_AGENT);
}
__device__ __forceinline__ void add_rel(int* p, int v) {
    __hip_atomic_fetch_add(p, v, __ATOMIC_RELEASE, __HIP_MEMORY_SCOPE_AGENT);
}

struct FpsSm {
    float4 p4[TD_P];                 // 64 KB
    int    sel[TD_S];                // 4 KB
    unsigned long long kw[2][4];     // parity-buffered per-wave argmax keys
};
struct GemmSm {
    float As[16 * 260];
    float Bs[16 * 128];
};
struct KnnSm {
    union {
        _Float16 x[2][32][264];      // [hi/lo][c][k], row pad 8 halfs (33792 B)
        float    dt[128][33];        // aliased after MFMA (16896 B)
    } u;
    float QQs[128];
    int   QR[128];
    float xxs[32];
};
struct MergeSm {
    float ld[32][130];               // 128 used, +2 pad (bank spread)
    int   li[32][130];
};
struct MaxpSm { int nbr[128]; };
union SmU {
    FpsSm f; GemmSm g; KnnSm k; MergeSm m; MaxpSm mp;   // 69,696 B -> 2 blk/CU
};

// One level of a wave64 max-reduce on a positive-double key via paired 32-bit
// DPP + v_max_f64 (key hi=fp32 bits of min_d, lo=~idx; positive finite
// doubles => fmax == bitwise u64 max, tie -> lowest idx).
#define TD_DPPSTEPD(kd_, ctl, bc)                                                       \
    {                                                                                   \
        long long ki_ = __double_as_longlong(kd_);                                      \
        unsigned yh_ = (unsigned)__builtin_amdgcn_update_dpp(                           \
            0, (int)((unsigned long long)ki_ >> 32), (ctl), 0xf, 0xf, (bc));            \
        unsigned yl_ = (unsigned)__builtin_amdgcn_update_dpp(                           \
            0, (int)(unsigned)(unsigned long long)ki_, (ctl), 0xf, 0xf, (bc));          \
        kd_ = fmax(kd_, __hiloint2double((int)yh_, (int)yl_));                          \
    }

__global__ __launch_bounds__(512, 4)
void td_all(const float* __restrict__ feat, const float* __restrict__ pos,
            const float* __restrict__ W, const float* __restrict__ bias,
            const float* __restrict__ gamma, const float* __restrict__ beta,
            unsigned short* __restrict__ H, int* __restrict__ FPSI,
            int* __restrict__ NN, float* __restrict__ P1, float* __restrict__ P2,
            float* __restrict__ SS, float* __restrict__ PD, int* __restrict__ PI,
            float* __restrict__ outF, float* __restrict__ outP,
            float* __restrict__ outB, int* __restrict__ flags) {
    __shared__ SmU sm;
    const int bx = blockIdx.x;
    const int t  = threadIdx.x;

    if (bx < 16) {
        // ================= FPS: round-0 core, 256 active threads =============
        __builtin_amdgcn_s_setprio(2);
        const int b = bx;
        const int w = t >> 6;
        v2f px[8], py[8], pz[8], md[8];
        int ni0[8], ni1[8];
        float lx = 0.0f, ly = 0.0f, lz = 0.0f;
        if (t < 256) {
#pragma unroll
            for (int j = 0; j < 8; ++j) {
                int p0 = j * 512 + t, p1 = p0 + 256;
                const float* q0 = pos + (size_t)(b * TD_P + p0) * 3;
                const float* q1 = pos + (size_t)(b * TD_P + p1) * 3;
                float x0 = q0[0], y0 = q0[1], z0 = q0[2];
                float x1 = q1[0], y1 = q1[1], z1 = q1[2];
                px[j] = (v2f){x0, x1}; py[j] = (v2f){y0, y1}; pz[j] = (v2f){z0, z1};
                sm.f.p4[p0] = make_float4(x0, y0, z0, 0.0f);
                sm.f.p4[p1] = make_float4(x1, y1, z1, 0.0f);
                md[j] = (v2f){__builtin_inff(), __builtin_inff()};
                ni0[j] = ~p0; ni1[j] = ~p1;
            }
            if (t == 0) sm.f.sel[0] = 0;
        }
        __syncthreads();
        if (t < 256) { float4 wp = sm.f.p4[0]; lx = wp.x; ly = wp.y; lz = wp.z; }
        for (int s = 0; s < TD_S - 1; ++s) {
            const int par = s & 1;
            if (t < 256) {
                double k[16];
                {
#pragma clang fp contract(off)
                    v2f l2x = (v2f){lx, lx}, l2y = (v2f){ly, ly}, l2z = (v2f){lz, lz};
#pragma unroll
                    for (int j = 0; j < 8; ++j) {
                        v2f dx = px[j] - l2x;
                        v2f dy = py[j] - l2y;
                        v2f dz = pz[j] - l2z;
                        v2f sx = dx * dx;
                        v2f sy = dy * dy;
                        v2f sz = dz * dz;
                        v2f dd = (sx + sy) + sz;
                        md[j] = __builtin_elementwise_min(md[j], dd);
                        k[2 * j]     = __hiloint2double(__float_as_int(md[j].x), ni0[j]);
                        k[2 * j + 1] = __hiloint2double(__float_as_int(md[j].y), ni1[j]);
                    }
                }
#pragma unroll
                for (int st = 8; st > 0; st >>= 1)
#pragma unroll
                    for (int i = 0; i < st; ++i) k[i] = fmax(k[i], k[i + st]);
                double tk = k[0];
                TD_DPPSTEPD(tk, 0x111, true)    // row_shr:1
                TD_DPPSTEPD(tk, 0x112, true)    // row_shr:2
                TD_DPPSTEPD(tk, 0x114, true)    // row_shr:4
                TD_DPPSTEPD(tk, 0x118, true)    // row_shr:8
                TD_DPPSTEPD(tk, 0x142, false)   // row_bcast:15
                TD_DPPSTEPD(tk, 0x143, false)   // row_bcast:31
                if ((t & 63) == 63)
                    sm.f.kw[par][w] = (unsigned long long)__double_as_longlong(tk);
            }
            __syncthreads();
            if (t < 256) {
                const double2* kd = (const double2*)sm.f.kw[par];
                double2 va = kd[0], vb = kd[1];
                double gk = fmax(fmax(va.x, va.y), fmax(vb.x, vb.y));
                unsigned idx = ~(unsigned)__double2loint(gk);
                if (t == 0) sm.f.sel[s + 1] = (int)idx;
                float4 wp = sm.f.p4[idx];
                lx = wp.x; ly = wp.y; lz = wp.z;
            }
            // publish chunk c = samples [c*128,(c+1)*128) (wave 0 only).
            if (t < 64 && (s & 127) == 127 && s < 896) {
                int c = s >> 7;
                int i0 = c * 128 + 2 * t;
                FPSI[b * TD_S + i0]     = b * TD_P + sm.f.sel[i0];
                FPSI[b * TD_S + i0 + 1] = b * TD_P + sm.f.sel[i0 + 1];
                __threadfence();
                if (t == 0) st_rel(flags + b, c + 1);
            }
        }
        __syncthreads();
        for (int s = t; s < TD_S; s += 512) {
            int li = sm.f.sel[s];
            int og = b * TD_S + s;
            float4 wp = sm.f.p4[li];
            outP[og * 3 + 0] = wp.x;
            outP[og * 3 + 1] = wp.y;
            outP[og * 3 + 2] = wp.z;
            outB[og] = (float)b;
            FPSI[og] = b * TD_P + li;
        }
        __syncthreads();
        if (t == 0) { __threadfence(); st_rel(flags + b, 8); }
    } else if (bx < 1040) {
        // ================= MLP GEMM: 256x128 tile, 8x8 micro =================
        const int gb = bx - 16;
        const int mb = gb >> 2, nb = gb & 3;
        const int tm = t >> 4, tn = t & 15;
        float acc[8][8];
#pragma unroll
        for (int i = 0; i < 8; ++i)
#pragma unroll
            for (int j = 0; j < 8; ++j) acc[i][j] = 0.0f;
        float* As = sm.g.As;
        float* Bs = sm.g.Bs;
        for (int kc = 0; kc < 16; ++kc) {
#pragma unroll
            for (int p2 = 0; p2 < 2; ++p2) {
                int f4 = t + 512 * p2;
                int r = f4 >> 2, c4 = f4 & 3;
                float4 v = *(const float4*)&feat[(size_t)(mb * 256 + r) * 256 + kc * 16 + c4 * 4];
                As[(c4 * 4 + 0) * 260 + r] = v.x;
                As[(c4 * 4 + 1) * 260 + r] = v.y;
                As[(c4 * 4 + 2) * 260 + r] = v.z;
                As[(c4 * 4 + 3) * 260 + r] = v.w;
            }
            {
                int kk = t >> 5, n4 = t & 31;
                float4 v = *(const float4*)&W[(size_t)(kc * 16 + kk) * 512 + nb * 128 + n4 * 4];
                *(float4*)&Bs[kk * 128 + n4 * 4] = v;
            }
            __syncthreads();
#pragma unroll
            for (int kk = 0; kk < 16; ++kk) {
                float4 a0 = *(float4*)&As[kk * 260 + tm * 8];
                float4 a1 = *(float4*)&As[kk * 260 + tm * 8 + 4];
                float4 b0 = *(float4*)&Bs[kk * 128 + tn * 8];
                float4 b1 = *(float4*)&Bs[kk * 128 + tn * 8 + 4];
                float av[8] = {a0.x, a0.y, a0.z, a0.w, a1.x, a1.y, a1.z, a1.w};
                float bv2[8] = {b0.x, b0.y, b0.z, b0.w, b1.x, b1.y, b1.z, b1.w};
#pragma unroll
                for (int i = 0; i < 8; ++i)
#pragma unroll
                    for (int j = 0; j < 8; ++j)
                        acc[i][j] = fmaf(av[i], bv2[j], acc[i][j]);
            }
            __syncthreads();
        }
        float4 bb0 = *(const float4*)&bias[nb * 128 + tn * 8];
        float4 bb1 = *(const float4*)&bias[nb * 128 + tn * 8 + 4];
        float bsv[8] = {bb0.x, bb0.y, bb0.z, bb0.w, bb1.x, bb1.y, bb1.z, bb1.w};
#pragma unroll
        for (int i = 0; i < 8; ++i) {
            int row = mb * 256 + tm * 8 + i;
            uint4 pk;
            pk.x = (unsigned)f2bf(acc[i][0] + bsv[0]) | ((unsigned)f2bf(acc[i][1] + bsv[1]) << 16);
            pk.y = (unsigned)f2bf(acc[i][2] + bsv[2]) | ((unsigned)f2bf(acc[i][3] + bsv[3]) << 16);
            pk.z = (unsigned)f2bf(acc[i][4] + bsv[4]) | ((unsigned)f2bf(acc[i][5] + bsv[5]) << 16);
            pk.w = (unsigned)f2bf(acc[i][6] + bsv[6]) | ((unsigned)f2bf(acc[i][7] + bsv[7]) << 16);
            *(uint4*)&H[(size_t)row * 512 + nb * 128 + tn * 8] = pk;
        }
        __syncthreads();
        if (t == 0) { __threadfence(); add_rel(flags + 16, 1); }
    } else if (bx < 1296) {
        // ================= BN partial sums (needs all GEMM) ==================
        const int rb = bx - 1040;
        if (t == 0) {
            while (ld_acq(flags + 16) < 1024) __builtin_amdgcn_s_sleep(32);
        }
        __syncthreads();
        if (t < 256) {
            float s1a = 0, s2a = 0, s1b = 0, s2b = 0;
            for (int r = 0; r < 256; ++r) {
                const unsigned* hp = (const unsigned*)(H + (size_t)(rb * 256 + r) * 512);
                unsigned u = hp[t];
                float lo = __uint_as_float(u << 16);
                float hi = __uint_as_float(u & 0xffff0000u);
                s1a += lo; s2a = fmaf(lo, lo, s2a);
                s1b += hi; s2b = fmaf(hi, hi, s2b);
            }
            P1[rb * 512 + 2 * t] = s1a; P1[rb * 512 + 2 * t + 1] = s1b;
            P2[rb * 512 + 2 * t] = s2a; P2[rb * 512 + 2 * t + 1] = s2b;
        }
        __syncthreads();
        if (t == 0) { __threadfence(); add_rel(flags + 17, 1); }
    } else if (bx == 1296) {
        // ================= BN finalize -> scale/shift ========================
        if (t == 0) {
            while (ld_acq(flags + 17) < 256) __builtin_amdgcn_s_sleep(32);
        }
        __syncthreads();
        {
            const int ch = t;
            float s1 = 0, s2 = 0;
            for (int rb2 = 0; rb2 < 256; ++rb2) {
                s1 += P1[rb2 * 512 + ch]; s2 += P2[rb2 * 512 + ch];
            }
            const float invN = 1.0f / 65536.0f;
            float mu  = s1 * invN;
            float var = s2 * invN - mu * mu;
            float sc  = gamma[ch] * (1.0f / sqrtf(var + 1e-5f));
            float sh  = beta[ch] - mu * sc;
            SS[ch] = sc; SS[512 + ch] = sh;
        }
        __syncthreads();
        if (t == 0) { __threadfence(); st_rel(flags + 18, 1); }
    } else if (bx < 2193 || (bx >= 4433 && bx < 4561)) {
        // ================= KNN: 128q chunk x 512c segment ====================
        int c, r;
        if (bx < 2193) { int kb = bx - 1297; c = kb >> 7; r = kb & 127; }
        else           { r = bx - 4433; c = 7; }
        const int b = r & 15, seg = r >> 4;
        const int qbase = b * TD_S + c * 128;
        const int segbase = b * TD_P + seg * 512;
        if (t == 0) {
            while (ld_acq(flags + b) < c + 1) __builtin_amdgcn_s_sleep(16);
        }
        __syncthreads();
        if (t < 128) sm.k.QR[t] = FPSI[qbase + t];
        __syncthreads();

        const int w = t >> 6, lane = t & 63;
        const int m = lane & 15, quad = lane >> 4;

        // Q fragments: wave w owns queries [w*16, w*16+16)
        half8 qh[8], ql[8];
        {
            const float* qp = feat + (size_t)sm.k.QR[w * 16 + m] * 256;
            float qq2 = 0.0f;
#pragma unroll
            for (int ks = 0; ks < 8; ++ks) {
                float4 f0 = *(const float4*)(qp + ks * 32 + quad * 8);
                float4 f1 = *(const float4*)(qp + ks * 32 + quad * 8 + 4);
                float fv[8] = {f0.x, f0.y, f0.z, f0.w, f1.x, f1.y, f1.z, f1.w};
                half8 h, l;
#pragma unroll
                for (int j = 0; j < 8; ++j) {
                    _Float16 hv = (_Float16)fv[j];
                    h[j] = hv;
                    l[j] = (_Float16)(fv[j] - (float)hv);
                    qq2 = fmaf(fv[j], fv[j], qq2);
                }
                qh[ks] = h; ql[ks] = l;
            }
            qq2 += __shfl_xor(qq2, 16, 64);
            qq2 += __shfl_xor(qq2, 32, 64);
            if (quad == 0) sm.k.QQs[w * 16 + m] = qq2;
        }

        float sd[16]; int si[16];
#pragma unroll
        for (int rr = 0; rr < 16; ++rr) { sd[rr] = __builtin_inff(); si[rr] = 0x7fffffff; }

        const int xrow = t >> 4, part = t & 15;

        for (int ct = 0; ct < 16; ++ct) {
            __syncthreads();   // selection done reading dt (aliases x)
            // ---- stage 32 cands x 256k fp32->fp16 hi/lo + cand norms --------
            {
                const float* xp = feat + (size_t)(segbase + ct * 32 + xrow) * 256 + part * 16;
                float4 f0 = *(const float4*)(xp);
                float4 f1 = *(const float4*)(xp + 4);
                float4 f2 = *(const float4*)(xp + 8);
                float4 f3 = *(const float4*)(xp + 12);
                float fv[16] = {f0.x, f0.y, f0.z, f0.w, f1.x, f1.y, f1.z, f1.w,
                                f2.x, f2.y, f2.z, f2.w, f3.x, f3.y, f3.z, f3.w};
                half8 h0, h1, l0, l1;
                float cn = 0.0f;
#pragma unroll
                for (int j = 0; j < 8; ++j) {
                    _Float16 hv = (_Float16)fv[j];
                    h0[j] = hv; l0[j] = (_Float16)(fv[j] - (float)hv);
                    cn = fmaf(fv[j], fv[j], cn);
                }
#pragma unroll
                for (int j = 0; j < 8; ++j) {
                    float v = fv[8 + j];
                    _Float16 hv = (_Float16)v;
                    h1[j] = hv; l1[j] = (_Float16)(v - (float)hv);
                    cn = fmaf(v, v, cn);
                }
                *(half8*)&sm.k.u.x[0][xrow][part * 16]     = h0;
                *(half8*)&sm.k.u.x[0][xrow][part * 16 + 8] = h1;
                *(half8*)&sm.k.u.x[1][xrow][part * 16]     = l0;
                *(half8*)&sm.k.u.x[1][xrow][part * 16 + 8] = l1;
                cn += __shfl_xor(cn, 1, 64);
                cn += __shfl_xor(cn, 2, 64);
                cn += __shfl_xor(cn, 4, 64);
                cn += __shfl_xor(cn, 8, 64);
                if (part == 0) sm.k.xxs[xrow] = cn;
            }
            __syncthreads();
            // ---- MFMA: 4 chains = [cand-half][ks-parity] --------------------
            f32x4 a00 = (f32x4)0.0f, a01 = (f32x4)0.0f;
            f32x4 a10 = (f32x4)0.0f, a11 = (f32x4)0.0f;
#pragma unroll
            for (int k2 = 0; k2 < 4; ++k2) {
                const int ka = 2 * k2, kb2 = 2 * k2 + 1;
                half8 xh0a = *(half8*)&sm.k.u.x[0][m][ka * 32 + quad * 8];
                half8 xl0a = *(half8*)&sm.k.u.x[1][m][ka * 32 + quad * 8];
                half8 xh1a = *(half8*)&sm.k.u.x[0][16 + m][ka * 32 + quad * 8];
                half8 xl1a = *(half8*)&sm.k.u.x[1][16 + m][ka * 32 + quad * 8];
                half8 xh0b = *(half8*)&sm.k.u.x[0][m][kb2 * 32 + quad * 8];
                half8 xl0b = *(half8*)&sm.k.u.x[1][m][kb2 * 32 + quad * 8];
                half8 xh1b = *(half8*)&sm.k.u.x[0][16 + m][kb2 * 32 + quad * 8];
                half8 xl1b = *(half8*)&sm.k.u.x[1][16 + m][kb2 * 32 + quad * 8];
                a00 = __builtin_amdgcn_mfma_f32_16x16x32_f16(ql[ka],  xh0a, a00, 0, 0, 0);
                a10 = __builtin_amdgcn_mfma_f32_16x16x32_f16(ql[ka],  xh1a, a10, 0, 0, 0);
                a01 = __builtin_amdgcn_mfma_f32_16x16x32_f16(ql[kb2], xh0b, a01, 0, 0, 0);
                a11 = __builtin_amdgcn_mfma_f32_16x16x32_f16(ql[kb2], xh1b, a11, 0, 0, 0);
                a00 = __builtin_amdgcn_mfma_f32_16x16x32_f16(qh[ka],  xl0a, a00, 0, 0, 0);
                a10 = __builtin_amdgcn_mfma_f32_16x16x32_f16(qh[ka],  xl1a, a10, 0, 0, 0);
                a01 = __builtin_amdgcn_mfma_f32_16x16x32_f16(qh[kb2], xl0b, a01, 0, 0, 0);
                a11 = __builtin_amdgcn_mfma_f32_16x16x32_f16(qh[kb2], xl1b, a11, 0, 0, 0);
                a00 = __builtin_amdgcn_mfma_f32_16x16x32_f16(qh[ka],  xh0a, a00, 0, 0, 0);
                a10 = __builtin_amdgcn_mfma_f32_16x16x32_f16(qh[ka],  xh1a, a10, 0, 0, 0);
                a01 = __builtin_amdgcn_mfma_f32_16x16x32_f16(qh[kb2], xh0b, a01, 0, 0, 0);
                a11 = __builtin_amdgcn_mfma_f32_16x16x32_f16(qh[kb2], xh1b, a11, 0, 0, 0);
            }
            __syncthreads();   // all waves done reading x; safe to alias dt
            // ---- epilogue: d = (qq - 2S) + xx -> dt -------------------------
            {
                float xx0 = sm.k.xxs[m];
                float xx1 = sm.k.xxs[16 + m];
                int qb = w * 16 + quad * 4;
#pragma unroll
                for (int reg = 0; reg < 4; ++reg) {
                    float qq = sm.k.QQs[qb + reg];
                    float S0 = a00[reg] + a01[reg];
                    float S1 = a10[reg] + a11[reg];
                    sm.k.u.dt[qb + reg][m]      = (qq - 2.0f * S0) + xx0;
                    sm.k.u.dt[qb + reg][16 + m] = (qq - 2.0f * S1) + xx1;
                }
            }
            __syncthreads();
            // ---- selection: thread t (<128) owns query t --------------------
            if (t < 128) {
                const int ibase = segbase + ct * 32;
                for (int j = 0; j < 32; ++j) {
                    float d = sm.k.u.dt[t][j];
                    if (d < sd[15]) {
                        sd[15] = d; si[15] = ibase + j;
#pragma unroll
                        for (int rr = 15; rr > 0; --rr) {
                            if (sd[rr] < sd[rr - 1]) {
                                float td2 = sd[rr]; sd[rr] = sd[rr - 1]; sd[rr - 1] = td2;
                                int ti = si[rr]; si[rr] = si[rr - 1]; si[rr - 1] = ti;
                            }
                        }
                    }
                }
            }
        }
        if (t < 128) {
            size_t o = ((size_t)(qbase + t)) * 128 + seg * 16;
#pragma unroll
            for (int rr = 0; rr < 16; ++rr) { PD[o + rr] = sd[rr]; PI[o + rr] = si[rr]; }
        }
        __syncthreads();
        if (t == 0) { __threadfence(); add_rel(flags + 32 + b * 8 + c, 1); }
    } else if (bx < 2641 || (bx >= 4561 && bx < 4625)) {
        // ================= merge: 32 queries, 8 segs x 16 ====================
        int mb, g;
        if (bx < 2641) { mb = bx - 2193; g = mb >> 4; }
        else           { mb = bx - 4561; g = 28 + (mb >> 4); }
        const int b = mb & 15;
        const int qg = b * TD_S + g * 32;
        if (t == 0) {
            while (ld_acq(flags + 32 + b * 8 + (g >> 2)) < 8) __builtin_amdgcn_s_sleep(16);
        }
        __syncthreads();
        for (int i = t; i < 32 * 128; i += 512) {
            int qi = i >> 7, j = i & 127;
            sm.m.ld[qi][j] = PD[(size_t)qg * 128 + i];
            sm.m.li[qi][j] = PI[(size_t)qg * 128 + i];
        }
        __syncthreads();
        if (t < 32) {
            float sd[16]; int si[16];
#pragma unroll
            for (int rr = 0; rr < 16; ++rr) { sd[rr] = __builtin_inff(); si[rr] = 0x7fffffff; }
            // seg-major ascending scan = ascending global index; strict-<
            // insertion keeps lowest index on ties (matches lax.top_k).
            for (int j = 0; j < 128; ++j) {
                float d = sm.m.ld[t][j];
                if (d < sd[15]) {
                    sd[15] = d; si[15] = sm.m.li[t][j];
#pragma unroll
                    for (int rr = 15; rr > 0; --rr) {
                        if (sd[rr] < sd[rr - 1]) {
                            float td2 = sd[rr]; sd[rr] = sd[rr - 1]; sd[rr - 1] = td2;
                            int ti = si[rr]; si[rr] = si[rr - 1]; si[rr - 1] = ti;
                        }
                    }
                }
            }
            int og = (qg + t) * TD_K;
#pragma unroll
            for (int rr = 0; rr < 16; ++rr) NN[og + rr] = si[rr];
        }
        __syncthreads();
        if (t == 0) { __threadfence(); st_rel(flags + 192 + b * 32 + g, 1); }
    } else {
        // ================= maxpool: 8 queries/block ==========================
        int pb, k;
        if (bx < 4433) { pb = bx - 2641; k = pb >> 4; }
        else           { pb = bx - 4625; k = 112 + (pb >> 4); }
        const int b = pb & 15;
        const int qbase8 = b * TD_S + k * 8;
        const int g = k >> 2;
        if (t == 0) {
            while (ld_acq(flags + 192 + b * 32 + g) == 0) __builtin_amdgcn_s_sleep(16);
            while (ld_acq(flags + 18) == 0) __builtin_amdgcn_s_sleep(16);
        }
        __syncthreads();
        if (t < 128) sm.mp.nbr[t] = NN[(size_t)qbase8 * 16 + t];
        __syncthreads();
        const int hq = t >> 8, tc = t & 255;
        float sc0 = SS[2 * tc], sc1 = SS[2 * tc + 1];
        float sh0 = SS[512 + 2 * tc], sh1 = SS[512 + 2 * tc + 1];
#pragma unroll
        for (int qi = 0; qi < 4; ++qi) {
            const int q = hq * 4 + qi;
            float m0 = 0.0f, m1 = 0.0f;   // relu floor
#pragma unroll
            for (int kk = 0; kk < 16; ++kk) {
                int row = sm.mp.nbr[q * 16 + kk];
                unsigned u = ((const unsigned*)(H + (size_t)row * 512))[tc];
                float lo = __uint_as_float(u << 16);
                float hi = __uint_as_float(u & 0xffff0000u);
                m0 = fmaxf(m0, fmaf(sc0, lo, sh0));
                m1 = fmaxf(m1, fmaf(sc1, hi, sh1));
            }
            float2 o; o.x = m0; o.y = m1;
            *(float2*)&outF[(size_t)(qbase8 + q) * 512 + 2 * tc] = o;
        }
    }
}

extern "C" void kernel_launch(void* const* d_in, const int* in_sizes, int n_in,
                              void* d_out, int out_size, void* d_ws, size_t ws_size,
                              hipStream_t stream) {
    const float* feat  = (const float*)d_in[0];
    const float* pos   = (const float*)d_in[1];
    // d_in[2] = batch (int32): unused, value is row/P by construction
    const float* W     = (const float*)d_in[3];
    const float* bias  = (const float*)d_in[4];
    const float* gamma = (const float*)d_in[5];
    const float* beta  = (const float*)d_in[6];

    char* ws = (char*)d_ws;
    int* flags        = (int*)ws;                        //      4,096 B (memset)
    unsigned short* H = (unsigned short*)(ws + 4096);    // 67,108,864 B
    int*   FPSI = (int*)  (ws + 67112960);               //     65,536 B
    int*   NN   = (int*)  (ws + 67178496);               //  1,048,576 B
    float* P1   = (float*)(ws + 68227072);               //    524,288 B
    float* P2   = (float*)(ws + 68751360);               //    524,288 B
    float* SS   = (float*)(ws + 69275648);               //      4,096 B
    float* PD   = (float*)(ws + 69279744);               //  8,388,608 B
    int*   PI   = (int*)  (ws + 77668352);               //  8,388,608 B

    float* outF = (float*)d_out;
    float* outP = outF + (size_t)TD_B * TD_S * TD_OUTF;
    float* outB = outP + (size_t)TD_B * TD_S * 3;

    hipMemsetAsync(flags, 0, 4096, stream);
    td_all<<<4881, 512, 0, stream>>>(feat, pos, W, bias, gamma, beta,
                                     H, FPSI, NN, P1, P2, SS, PD, PI,
                                     outF, outP, outB, flags);
}

// Round 5
// 1368.861 us; speedup vs baseline: 1.2298x; 1.2298x over previous
//
#include <hip/hip_runtime.h>
#include <cstddef>

// TransitionDown: B=16 clouds, P=4096 pts, S=1024 fps samples, K=16 knn,
// IN_F=256, OUT_F=512.
//
// SINGLE mega-kernel, flag-sequenced. v3: plain launch_bounds(512) (VGPR=128,
// no spills -- r4's (512,4) forced VGPR=64 and spilled FPS/KNN to scratch),
// un-padded 69.7KB union -> 2 blocks/CU, KNN at proven 256q x 512c blocks.
// Only the last 256-query chunk depends on FPS completion; it and its
// merges/maxpools are dispatched last so the post-FPS remainder is one
// fine-grained round.
// Block-index layout (producers strictly before consumers => deadlock-free
// under in-order dispatch):
//   [0,16)        FPS (round-0 core) + publish every 128 samples
//   [16,1040)     MLP GEMM fp32 -> h bf16
//   [1040,1296)   BN partial sums (spin: gemm)
//   [1296]        BN finalize (spin: stats)
//   [1297,1681)   KNN chunks 0..2 (3 x 16 x 8 blocks of 256q x 512c)
//   [1681,2065)   merge groups 0..23 (32q, 8-seg exact merge)
//   [2065,3601)   maxpool queries [0,768) (8q/block)
//   [3601,3729)   KNN chunk 3 (16 x 8)
//   [3729,3857)   merge groups 24..31
//   [3857,4369)   maxpool queries [768,1024)
// flags: [0..15] fps chunks done, [16] gemm cnt, [17] stats cnt, [18] bnfin,
// [32+b*4+c] knn seg cnt (target 8), [192+b*32+g] merge done.

#define TD_B   16
#define TD_P   4096
#define TD_S   1024
#define TD_K   16
#define TD_INF 256
#define TD_OUTF 512

typedef __attribute__((ext_vector_type(8))) _Float16 half8;
typedef __attribute__((ext_vector_type(4))) float    f32x4;
typedef __attribute__((ext_vector_type(2))) float    v2f;

__device__ __forceinline__ unsigned short f2bf(float x) {
    unsigned u = __float_as_uint(x);
    unsigned r = (u + 0x7fffu + ((u >> 16) & 1u)) >> 16;   // RNE
    return (unsigned short)r;
}

__device__ __forceinline__ int ld_acq(const int* p) {
    return __hip_atomic_load(p, __ATOMIC_ACQUIRE, __HIP_MEMORY_SCOPE_AGENT);
}
__device__ __forceinline__ void st_rel(int* p, int v) {
    __hip_atomic_store(p, v, __ATOMIC_RELEASE, __HIP_MEMORY_SCOPE_AGENT);
}
__device__ __forceinline__ void add_rel(int* p, int v) {
    __hip_atomic_fetch_add(p, v, __ATOMIC_RELEASE, __HIP_MEMORY_SCOPE_AGENT);
}

struct FpsSm {
    float4 p4[TD_P];                 // 64 KB
    int    sel[TD_S];                // 4 KB
    unsigned long long kw[2][4];     // parity-buffered per-wave argmax keys
};
struct GemmSm {
    float As[16 * 260];
    float Bs[16 * 128];
};
struct KnnSm {
    union {
        _Float16 x[2][32][264];      // [hi/lo][c][k], row pad 8 halfs (33792 B)
        float    dt[256][33];        // aliased after MFMA (33792 B)
    } u;
    float QQs[256];
    int   QR[256];
    float xxs[32];
};
struct MergeSm {
    float ld[32][130];               // 128 used, +2 pad (bank spread)
    int   li[32][130];
};
struct MaxpSm { int nbr[128]; };
union SmU {
    FpsSm f; GemmSm g; KnnSm k; MergeSm m; MaxpSm mp;   // 69,696 B -> 2 blk/CU
};

// One level of a wave64 max-reduce on a positive-double key via paired 32-bit
// DPP + v_max_f64 (key hi=fp32 bits of min_d, lo=~idx; positive finite
// doubles => fmax == bitwise u64 max, tie -> lowest idx).
#define TD_DPPSTEPD(kd_, ctl, bc)                                                       \
    {                                                                                   \
        long long ki_ = __double_as_longlong(kd_);                                      \
        unsigned yh_ = (unsigned)__builtin_amdgcn_update_dpp(                           \
            0, (int)((unsigned long long)ki_ >> 32), (ctl), 0xf, 0xf, (bc));            \
        unsigned yl_ = (unsigned)__builtin_amdgcn_update_dpp(                           \
            0, (int)(unsigned)(unsigned long long)ki_, (ctl), 0xf, 0xf, (bc));          \
        kd_ = fmax(kd_, __hiloint2double((int)yh_, (int)yl_));                          \
    }

__global__ __launch_bounds__(512)
void td_all(const float* __restrict__ feat, const float* __restrict__ pos,
            const float* __restrict__ W, const float* __restrict__ bias,
            const float* __restrict__ gamma, const float* __restrict__ beta,
            unsigned short* __restrict__ H, int* __restrict__ FPSI,
            int* __restrict__ NN, float* __restrict__ P1, float* __restrict__ P2,
            float* __restrict__ SS, float* __restrict__ PD, int* __restrict__ PI,
            float* __restrict__ outF, float* __restrict__ outP,
            float* __restrict__ outB, int* __restrict__ flags) {
    __shared__ SmU sm;
    const int bx = blockIdx.x;
    const int t  = threadIdx.x;

    if (bx < 16) {
        // ================= FPS: round-0 core, 256 active threads =============
        __builtin_amdgcn_s_setprio(2);
        const int b = bx;
        const int w = t >> 6;
        v2f px[8], py[8], pz[8], md[8];
        int ni0[8], ni1[8];
        float lx = 0.0f, ly = 0.0f, lz = 0.0f;
        if (t < 256) {
#pragma unroll
            for (int j = 0; j < 8; ++j) {
                int p0 = j * 512 + t, p1 = p0 + 256;
                const float* q0 = pos + (size_t)(b * TD_P + p0) * 3;
                const float* q1 = pos + (size_t)(b * TD_P + p1) * 3;
                float x0 = q0[0], y0 = q0[1], z0 = q0[2];
                float x1 = q1[0], y1 = q1[1], z1 = q1[2];
                px[j] = (v2f){x0, x1}; py[j] = (v2f){y0, y1}; pz[j] = (v2f){z0, z1};
                sm.f.p4[p0] = make_float4(x0, y0, z0, 0.0f);
                sm.f.p4[p1] = make_float4(x1, y1, z1, 0.0f);
                md[j] = (v2f){__builtin_inff(), __builtin_inff()};
                ni0[j] = ~p0; ni1[j] = ~p1;
            }
            if (t == 0) sm.f.sel[0] = 0;
        }
        __syncthreads();
        if (t < 256) { float4 wp = sm.f.p4[0]; lx = wp.x; ly = wp.y; lz = wp.z; }
        for (int s = 0; s < TD_S - 1; ++s) {
            const int par = s & 1;
            if (t < 256) {
                double k[16];
                {
#pragma clang fp contract(off)
                    v2f l2x = (v2f){lx, lx}, l2y = (v2f){ly, ly}, l2z = (v2f){lz, lz};
#pragma unroll
                    for (int j = 0; j < 8; ++j) {
                        v2f dx = px[j] - l2x;
                        v2f dy = py[j] - l2y;
                        v2f dz = pz[j] - l2z;
                        v2f sx = dx * dx;
                        v2f sy = dy * dy;
                        v2f sz = dz * dz;
                        v2f dd = (sx + sy) + sz;
                        md[j] = __builtin_elementwise_min(md[j], dd);
                        k[2 * j]     = __hiloint2double(__float_as_int(md[j].x), ni0[j]);
                        k[2 * j + 1] = __hiloint2double(__float_as_int(md[j].y), ni1[j]);
                    }
                }
#pragma unroll
                for (int st = 8; st > 0; st >>= 1)
#pragma unroll
                    for (int i = 0; i < st; ++i) k[i] = fmax(k[i], k[i + st]);
                double tk = k[0];
                TD_DPPSTEPD(tk, 0x111, true)    // row_shr:1
                TD_DPPSTEPD(tk, 0x112, true)    // row_shr:2
                TD_DPPSTEPD(tk, 0x114, true)    // row_shr:4
                TD_DPPSTEPD(tk, 0x118, true)    // row_shr:8
                TD_DPPSTEPD(tk, 0x142, false)   // row_bcast:15
                TD_DPPSTEPD(tk, 0x143, false)   // row_bcast:31
                if ((t & 63) == 63)
                    sm.f.kw[par][w] = (unsigned long long)__double_as_longlong(tk);
            }
            __syncthreads();
            if (t < 256) {
                const double2* kd = (const double2*)sm.f.kw[par];
                double2 va = kd[0], vb = kd[1];
                double gk = fmax(fmax(va.x, va.y), fmax(vb.x, vb.y));
                unsigned idx = ~(unsigned)__double2loint(gk);
                if (t == 0) sm.f.sel[s + 1] = (int)idx;
                float4 wp = sm.f.p4[idx];
                lx = wp.x; ly = wp.y; lz = wp.z;
            }
            // publish chunk c = samples [c*128,(c+1)*128) (wave 0 only).
            if (t < 64 && (s & 127) == 127 && s < 896) {
                int c = s >> 7;
                int i0 = c * 128 + 2 * t;
                FPSI[b * TD_S + i0]     = b * TD_P + sm.f.sel[i0];
                FPSI[b * TD_S + i0 + 1] = b * TD_P + sm.f.sel[i0 + 1];
                __threadfence();
                if (t == 0) st_rel(flags + b, c + 1);
            }
        }
        __syncthreads();
        for (int s = t; s < TD_S; s += 512) {
            int li = sm.f.sel[s];
            int og = b * TD_S + s;
            float4 wp = sm.f.p4[li];
            outP[og * 3 + 0] = wp.x;
            outP[og * 3 + 1] = wp.y;
            outP[og * 3 + 2] = wp.z;
            outB[og] = (float)b;
            FPSI[og] = b * TD_P + li;
        }
        __syncthreads();
        if (t == 0) { __threadfence(); st_rel(flags + b, 8); }
    } else if (bx < 1040) {
        // ================= MLP GEMM: 256x128 tile, 8x8 micro =================
        const int gb = bx - 16;
        const int mb = gb >> 2, nb = gb & 3;
        const int tm = t >> 4, tn = t & 15;
        float acc[8][8];
#pragma unroll
        for (int i = 0; i < 8; ++i)
#pragma unroll
            for (int j = 0; j < 8; ++j) acc[i][j] = 0.0f;
        float* As = sm.g.As;
        float* Bs = sm.g.Bs;
        for (int kc = 0; kc < 16; ++kc) {
#pragma unroll
            for (int p2 = 0; p2 < 2; ++p2) {
                int f4 = t + 512 * p2;
                int r = f4 >> 2, c4 = f4 & 3;
                float4 v = *(const float4*)&feat[(size_t)(mb * 256 + r) * 256 + kc * 16 + c4 * 4];
                As[(c4 * 4 + 0) * 260 + r] = v.x;
                As[(c4 * 4 + 1) * 260 + r] = v.y;
                As[(c4 * 4 + 2) * 260 + r] = v.z;
                As[(c4 * 4 + 3) * 260 + r] = v.w;
            }
            {
                int kk = t >> 5, n4 = t & 31;
                float4 v = *(const float4*)&W[(size_t)(kc * 16 + kk) * 512 + nb * 128 + n4 * 4];
                *(float4*)&Bs[kk * 128 + n4 * 4] = v;
            }
            __syncthreads();
#pragma unroll
            for (int kk = 0; kk < 16; ++kk) {
                float4 a0 = *(float4*)&As[kk * 260 + tm * 8];
                float4 a1 = *(float4*)&As[kk * 260 + tm * 8 + 4];
                float4 b0 = *(float4*)&Bs[kk * 128 + tn * 8];
                float4 b1 = *(float4*)&Bs[kk * 128 + tn * 8 + 4];
                float av[8] = {a0.x, a0.y, a0.z, a0.w, a1.x, a1.y, a1.z, a1.w};
                float bv2[8] = {b0.x, b0.y, b0.z, b0.w, b1.x, b1.y, b1.z, b1.w};
#pragma unroll
                for (int i = 0; i < 8; ++i)
#pragma unroll
                    for (int j = 0; j < 8; ++j)
                        acc[i][j] = fmaf(av[i], bv2[j], acc[i][j]);
            }
            __syncthreads();
        }
        float4 bb0 = *(const float4*)&bias[nb * 128 + tn * 8];
        float4 bb1 = *(const float4*)&bias[nb * 128 + tn * 8 + 4];
        float bsv[8] = {bb0.x, bb0.y, bb0.z, bb0.w, bb1.x, bb1.y, bb1.z, bb1.w};
#pragma unroll
        for (int i = 0; i < 8; ++i) {
            int row = mb * 256 + tm * 8 + i;
            uint4 pk;
            pk.x = (unsigned)f2bf(acc[i][0] + bsv[0]) | ((unsigned)f2bf(acc[i][1] + bsv[1]) << 16);
            pk.y = (unsigned)f2bf(acc[i][2] + bsv[2]) | ((unsigned)f2bf(acc[i][3] + bsv[3]) << 16);
            pk.z = (unsigned)f2bf(acc[i][4] + bsv[4]) | ((unsigned)f2bf(acc[i][5] + bsv[5]) << 16);
            pk.w = (unsigned)f2bf(acc[i][6] + bsv[6]) | ((unsigned)f2bf(acc[i][7] + bsv[7]) << 16);
            *(uint4*)&H[(size_t)row * 512 + nb * 128 + tn * 8] = pk;
        }
        __syncthreads();
        if (t == 0) { __threadfence(); add_rel(flags + 16, 1); }
    } else if (bx < 1296) {
        // ================= BN partial sums (needs all GEMM) ==================
        const int rb = bx - 1040;
        if (t == 0) {
            while (ld_acq(flags + 16) < 1024) __builtin_amdgcn_s_sleep(32);
        }
        __syncthreads();
        if (t < 256) {
            float s1a = 0, s2a = 0, s1b = 0, s2b = 0;
            for (int r = 0; r < 256; ++r) {
                const unsigned* hp = (const unsigned*)(H + (size_t)(rb * 256 + r) * 512);
                unsigned u = hp[t];
                float lo = __uint_as_float(u << 16);
                float hi = __uint_as_float(u & 0xffff0000u);
                s1a += lo; s2a = fmaf(lo, lo, s2a);
                s1b += hi; s2b = fmaf(hi, hi, s2b);
            }
            P1[rb * 512 + 2 * t] = s1a; P1[rb * 512 + 2 * t + 1] = s1b;
            P2[rb * 512 + 2 * t] = s2a; P2[rb * 512 + 2 * t + 1] = s2b;
        }
        __syncthreads();
        if (t == 0) { __threadfence(); add_rel(flags + 17, 1); }
    } else if (bx == 1296) {
        // ================= BN finalize -> scale/shift ========================
        if (t == 0) {
            while (ld_acq(flags + 17) < 256) __builtin_amdgcn_s_sleep(32);
        }
        __syncthreads();
        {
            const int ch = t;
            float s1 = 0, s2 = 0;
            for (int rb2 = 0; rb2 < 256; ++rb2) {
                s1 += P1[rb2 * 512 + ch]; s2 += P2[rb2 * 512 + ch];
            }
            const float invN = 1.0f / 65536.0f;
            float mu  = s1 * invN;
            float var = s2 * invN - mu * mu;
            float sc  = gamma[ch] * (1.0f / sqrtf(var + 1e-5f));
            float sh  = beta[ch] - mu * sc;
            SS[ch] = sc; SS[512 + ch] = sh;
        }
        __syncthreads();
        if (t == 0) { __threadfence(); st_rel(flags + 18, 1); }
    } else if (bx < 1681 || (bx >= 3601 && bx < 3729)) {
        // ================= KNN: 256q chunk x 512c segment ====================
        int c, r;
        if (bx < 1681) { int kb = bx - 1297; c = kb >> 7; r = kb & 127; }
        else           { r = bx - 3601; c = 3; }
        const int b = r & 15, seg = r >> 4;
        const int qbase = b * TD_S + c * 256;
        const int segbase = b * TD_P + seg * 512;
        if (t == 0) {
            while (ld_acq(flags + b) < 2 * c + 2) __builtin_amdgcn_s_sleep(16);
        }
        __syncthreads();
        if (t < 256) sm.k.QR[t] = FPSI[qbase + t];
        __syncthreads();

        const int w = t >> 6, lane = t & 63;
        const int m = lane & 15, quad = lane >> 4;

        // Q fragments (each wave owns 32 queries) + query norms via shuffles
        half8 qh[2][8], ql[2][8];
#pragma unroll
        for (int qs = 0; qs < 2; ++qs) {
            const float* qp = feat + (size_t)sm.k.QR[w * 32 + qs * 16 + m] * 256;
            float qq2 = 0.0f;
#pragma unroll
            for (int ks = 0; ks < 8; ++ks) {
                float4 f0 = *(const float4*)(qp + ks * 32 + quad * 8);
                float4 f1 = *(const float4*)(qp + ks * 32 + quad * 8 + 4);
                float fv[8] = {f0.x, f0.y, f0.z, f0.w, f1.x, f1.y, f1.z, f1.w};
                half8 h, l;
#pragma unroll
                for (int j = 0; j < 8; ++j) {
                    _Float16 hv = (_Float16)fv[j];
                    h[j] = hv;
                    l[j] = (_Float16)(fv[j] - (float)hv);
                    qq2 = fmaf(fv[j], fv[j], qq2);
                }
                qh[qs][ks] = h; ql[qs][ks] = l;
            }
            qq2 += __shfl_xor(qq2, 16, 64);
            qq2 += __shfl_xor(qq2, 32, 64);
            if (quad == 0) sm.k.QQs[w * 32 + qs * 16 + m] = qq2;
        }

        float sd[16]; int si[16];
#pragma unroll
        for (int rr = 0; rr < 16; ++rr) { sd[rr] = __builtin_inff(); si[rr] = 0x7fffffff; }

        const int xrow = t >> 4, part = t & 15;

        for (int ct = 0; ct < 16; ++ct) {
            __syncthreads();   // prev selection done reading dt (aliases x)
            // ---- stage 32 cands x 256k fp32->fp16 hi/lo + cand norms --------
            {
                const float* xp = feat + (size_t)(segbase + ct * 32 + xrow) * 256 + part * 16;
                float4 f0 = *(const float4*)(xp);
                float4 f1 = *(const float4*)(xp + 4);
                float4 f2 = *(const float4*)(xp + 8);
                float4 f3 = *(const float4*)(xp + 12);
                float fv[16] = {f0.x, f0.y, f0.z, f0.w, f1.x, f1.y, f1.z, f1.w,
                                f2.x, f2.y, f2.z, f2.w, f3.x, f3.y, f3.z, f3.w};
                half8 h0, h1, l0, l1;
                float cn = 0.0f;
#pragma unroll
                for (int j = 0; j < 8; ++j) {
                    _Float16 hv = (_Float16)fv[j];
                    h0[j] = hv; l0[j] = (_Float16)(fv[j] - (float)hv);
                    cn = fmaf(fv[j], fv[j], cn);
                }
#pragma unroll
                for (int j = 0; j < 8; ++j) {
                    float v = fv[8 + j];
                    _Float16 hv = (_Float16)v;
                    h1[j] = hv; l1[j] = (_Float16)(v - (float)hv);
                    cn = fmaf(v, v, cn);
                }
                *(half8*)&sm.k.u.x[0][xrow][part * 16]     = h0;
                *(half8*)&sm.k.u.x[0][xrow][part * 16 + 8] = h1;
                *(half8*)&sm.k.u.x[1][xrow][part * 16]     = l0;
                *(half8*)&sm.k.u.x[1][xrow][part * 16 + 8] = l1;
                cn += __shfl_xor(cn, 1, 64);
                cn += __shfl_xor(cn, 2, 64);
                cn += __shfl_xor(cn, 4, 64);
                cn += __shfl_xor(cn, 8, 64);
                if (part == 0) sm.k.xxs[xrow] = cn;
            }
            __syncthreads();
            // ---- MFMA: all 8 waves, pass-major, 4 independent acc chains ----
            f32x4 acc[2][2];
            acc[0][0] = (f32x4)0.0f; acc[0][1] = (f32x4)0.0f;
            acc[1][0] = (f32x4)0.0f; acc[1][1] = (f32x4)0.0f;
#pragma unroll
            for (int ks = 0; ks < 8; ++ks) {
                half8 xh0 = *(half8*)&sm.k.u.x[0][m][ks * 32 + quad * 8];
                half8 xl0 = *(half8*)&sm.k.u.x[1][m][ks * 32 + quad * 8];
                half8 xh1 = *(half8*)&sm.k.u.x[0][16 + m][ks * 32 + quad * 8];
                half8 xl1 = *(half8*)&sm.k.u.x[1][16 + m][ks * 32 + quad * 8];
                acc[0][0] = __builtin_amdgcn_mfma_f32_16x16x32_f16(ql[0][ks], xh0, acc[0][0], 0, 0, 0);
                acc[0][1] = __builtin_amdgcn_mfma_f32_16x16x32_f16(ql[0][ks], xh1, acc[0][1], 0, 0, 0);
                acc[1][0] = __builtin_amdgcn_mfma_f32_16x16x32_f16(ql[1][ks], xh0, acc[1][0], 0, 0, 0);
                acc[1][1] = __builtin_amdgcn_mfma_f32_16x16x32_f16(ql[1][ks], xh1, acc[1][1], 0, 0, 0);
                acc[0][0] = __builtin_amdgcn_mfma_f32_16x16x32_f16(qh[0][ks], xl0, acc[0][0], 0, 0, 0);
                acc[0][1] = __builtin_amdgcn_mfma_f32_16x16x32_f16(qh[0][ks], xl1, acc[0][1], 0, 0, 0);
                acc[1][0] = __builtin_amdgcn_mfma_f32_16x16x32_f16(qh[1][ks], xl0, acc[1][0], 0, 0, 0);
                acc[1][1] = __builtin_amdgcn_mfma_f32_16x16x32_f16(qh[1][ks], xl1, acc[1][1], 0, 0, 0);
                acc[0][0] = __builtin_amdgcn_mfma_f32_16x16x32_f16(qh[0][ks], xh0, acc[0][0], 0, 0, 0);
                acc[0][1] = __builtin_amdgcn_mfma_f32_16x16x32_f16(qh[0][ks], xh1, acc[0][1], 0, 0, 0);
                acc[1][0] = __builtin_amdgcn_mfma_f32_16x16x32_f16(qh[1][ks], xh0, acc[1][0], 0, 0, 0);
                acc[1][1] = __builtin_amdgcn_mfma_f32_16x16x32_f16(qh[1][ks], xh1, acc[1][1], 0, 0, 0);
            }
            __syncthreads();   // all waves done reading x; safe to alias as dt
            // ---- epilogue: d = (qq - 2S) + xx -> dt -------------------------
            {
                float xx0 = sm.k.xxs[m];
                float xx1 = sm.k.xxs[16 + m];
#pragma unroll
                for (int qs = 0; qs < 2; ++qs) {
                    int qb = w * 32 + qs * 16 + quad * 4;
#pragma unroll
                    for (int reg = 0; reg < 4; ++reg) {
                        float qq = sm.k.QQs[qb + reg];
                        sm.k.u.dt[qb + reg][m]      = (qq - 2.0f * acc[qs][0][reg]) + xx0;
                        sm.k.u.dt[qb + reg][16 + m] = (qq - 2.0f * acc[qs][1][reg]) + xx1;
                    }
                }
            }
            __syncthreads();
            // ---- selection: thread t (<256) owns query t --------------------
            if (t < 256) {
                const int ibase = segbase + ct * 32;
                for (int j = 0; j < 32; ++j) {
                    float d = sm.k.u.dt[t][j];
                    if (d < sd[15]) {
                        sd[15] = d; si[15] = ibase + j;
#pragma unroll
                        for (int rr = 15; rr > 0; --rr) {
                            if (sd[rr] < sd[rr - 1]) {
                                float td2 = sd[rr]; sd[rr] = sd[rr - 1]; sd[rr - 1] = td2;
                                int ti = si[rr]; si[rr] = si[rr - 1]; si[rr - 1] = ti;
                            }
                        }
                    }
                }
            }
        }
        if (t < 256) {
            size_t o = ((size_t)(qbase + t)) * 128 + seg * 16;
#pragma unroll
            for (int rr = 0; rr < 16; ++rr) { PD[o + rr] = sd[rr]; PI[o + rr] = si[rr]; }
        }
        __syncthreads();
        if (t == 0) { __threadfence(); add_rel(flags + 32 + b * 4 + c, 1); }
    } else if (bx < 2065 || (bx >= 3729 && bx < 3857)) {
        // ================= merge: 32 queries, 8 segs x 16 ====================
        int mb, g;
        if (bx < 2065) { mb = bx - 1681; g = mb >> 4; }
        else           { mb = bx - 3729; g = 24 + (mb >> 4); }
        const int b = mb & 15;
        const int qg = b * TD_S + g * 32;
        if (t == 0) {
            while (ld_acq(flags + 32 + b * 4 + (g >> 3)) < 8) __builtin_amdgcn_s_sleep(16);
        }
        __syncthreads();
        for (int i = t; i < 32 * 128; i += 512) {
            int qi = i >> 7, j = i & 127;
            sm.m.ld[qi][j] = PD[(size_t)qg * 128 + i];
            sm.m.li[qi][j] = PI[(size_t)qg * 128 + i];
        }
        __syncthreads();
        if (t < 32) {
            float sd[16]; int si[16];
#pragma unroll
            for (int rr = 0; rr < 16; ++rr) { sd[rr] = __builtin_inff(); si[rr] = 0x7fffffff; }
            // seg-major ascending scan = ascending global index; strict-<
            // insertion keeps lowest index on ties (matches lax.top_k).
            for (int j = 0; j < 128; ++j) {
                float d = sm.m.ld[t][j];
                if (d < sd[15]) {
                    sd[15] = d; si[15] = sm.m.li[t][j];
#pragma unroll
                    for (int rr = 15; rr > 0; --rr) {
                        if (sd[rr] < sd[rr - 1]) {
                            float td2 = sd[rr]; sd[rr] = sd[rr - 1]; sd[rr - 1] = td2;
                            int ti = si[rr]; si[rr] = si[rr - 1]; si[rr - 1] = ti;
                        }
                    }
                }
            }
            int og = (qg + t) * TD_K;
#pragma unroll
            for (int rr = 0; rr < 16; ++rr) NN[og + rr] = si[rr];
        }
        __syncthreads();
        if (t == 0) { __threadfence(); st_rel(flags + 192 + b * 32 + g, 1); }
    } else {
        // ================= maxpool: 8 queries/block ==========================
        int pb, k;
        if (bx < 3601) { pb = bx - 2065; k = pb >> 4; }
        else           { pb = bx - 3857; k = 96 + (pb >> 4); }
        const int b = pb & 15;
        const int qbase8 = b * TD_S + k * 8;
        const int g = k >> 2;
        if (t == 0) {
            while (ld_acq(flags + 192 + b * 32 + g) == 0) __builtin_amdgcn_s_sleep(16);
            while (ld_acq(flags + 18) == 0) __builtin_amdgcn_s_sleep(16);
        }
        __syncthreads();
        if (t < 128) sm.mp.nbr[t] = NN[(size_t)qbase8 * 16 + t];
        __syncthreads();
        const int hq = t >> 8, tc = t & 255;
        float sc0 = SS[2 * tc], sc1 = SS[2 * tc + 1];
        float sh0 = SS[512 + 2 * tc], sh1 = SS[512 + 2 * tc + 1];
#pragma unroll
        for (int qi = 0; qi < 4; ++qi) {
            const int q = hq * 4 + qi;
            float m0 = 0.0f, m1 = 0.0f;   // relu floor
#pragma unroll
            for (int kk = 0; kk < 16; ++kk) {
                int row = sm.mp.nbr[q * 16 + kk];
                unsigned u = ((const unsigned*)(H + (size_t)row * 512))[tc];
                float lo = __uint_as_float(u << 16);
                float hi = __uint_as_float(u & 0xffff0000u);
                m0 = fmaxf(m0, fmaf(sc0, lo, sh0));
                m1 = fmaxf(m1, fmaf(sc1, hi, sh1));
            }
            float2 o; o.x = m0; o.y = m1;
            *(float2*)&outF[(size_t)(qbase8 + q) * 512 + 2 * tc] = o;
        }
    }
}

extern "C" void kernel_launch(void* const* d_in, const int* in_sizes, int n_in,
                              void* d_out, int out_size, void* d_ws, size_t ws_size,
                              hipStream_t stream) {
    const float* feat  = (const float*)d_in[0];
    const float* pos   = (const float*)d_in[1];
    // d_in[2] = batch (int32): unused, value is row/P by construction
    const float* W     = (const float*)d_in[3];
    const float* bias  = (const float*)d_in[4];
    const float* gamma = (const float*)d_in[5];
    const float* beta  = (const float*)d_in[6];

    char* ws = (char*)d_ws;
    int* flags        = (int*)ws;                        //      4,096 B (memset)
    unsigned short* H = (unsigned short*)(ws + 4096);    // 67,108,864 B
    int*   FPSI = (int*)  (ws + 67112960);               //     65,536 B
    int*   NN   = (int*)  (ws + 67178496);               //  1,048,576 B
    float* P1   = (float*)(ws + 68227072);               //    524,288 B
    float* P2   = (float*)(ws + 68751360);               //    524,288 B
    float* SS   = (float*)(ws + 69275648);               //      4,096 B
    float* PD   = (float*)(ws + 69279744);               //  8,388,608 B
    int*   PI   = (int*)  (ws + 77668352);               //  8,388,608 B

    float* outF = (float*)d_out;
    float* outP = outF + (size_t)TD_B * TD_S * TD_OUTF;
    float* outB = outP + (size_t)TD_B * TD_S * 3;

    hipMemsetAsync(flags, 0, 4096, stream);
    td_all<<<4369, 512, 0, stream>>>(feat, pos, W, bias, gamma, beta,
                                     H, FPSI, NN, P1, P2, SS, PD, PI,
                                     outF, outP, outB, flags);
}